// Round 8
// baseline (453.701 us; speedup 1.0000x reference)
//
#include <hip/hip_runtime.h>
#include <math.h>

typedef __bf16 bf16;
typedef __bf16 bf16x8 __attribute__((ext_vector_type(8)));
typedef float f32x4 __attribute__((ext_vector_type(4)));

#define HEADS 16
#define QHEAD 192
#define NB 2
#define SEQ 2048
#define ROWS (NB * SEQ)
/* q pre-scale = log2(e)/sqrt(192): scores arrive in exp2 domain */
#define QSCALE2 0.10411754584f
/* fixed softmax shift: p = 2^(sacc - CSHIFT) = exp(s_nat - 8) */
#define CSHIFT 11.5415603272f
/* log2(10000)/32 — rope theta_i = 2^(-i * L2B32) */
#define L2B32 0.41524101186092029f
/* 1/(2*pi) — radians -> revolutions for v_sin/v_cos */
#define INV2PI 0.15915494309189535f

// fast RoPE sincos: theta_rev premultiplied by 1/2pi; v_sin/v_cos take
// revolutions, range-reduced with fract. Angle error ~2e-4 rad << bf16
// rounding. Verified rounds 5-7 (absmax 0.0156).
__device__ __forceinline__ void rope_sincos(float n, float theta_rev,
                                            float& sn, float& cs)
{
    float rev = n * theta_rev;
    rev -= floorf(rev);
    sn = __builtin_amdgcn_sinf(rev);
    cs = __builtin_amdgcn_cosf(rev);
}

// ---------------------------------------------------------------------------
// prep: fp32->bf16 convert of x (tiles 0..8191) + all 5 weight transposes
// ---------------------------------------------------------------------------
__global__ __launch_bounds__(256) void prep(
    const float* __restrict__ x,
    const float* __restrict__ Wqa, const float* __restrict__ Wqb,
    const float* __restrict__ Wkva, const float* __restrict__ Wkvb,
    const float* __restrict__ Wout,
    bf16* __restrict__ xb,
    bf16* __restrict__ WfT, bf16* __restrict__ WqbT,
    bf16* __restrict__ WkvbT, bf16* __restrict__ WoutT)
{
    int t = blockIdx.x;
    if (t < 8192) {
        size_t i = ((size_t)t * 256 + threadIdx.x) * 4;
        float4 v = *(const float4*)(x + i);
        xb[i]     = (bf16)v.x;
        xb[i + 1] = (bf16)v.y;
        xb[i + 2] = (bf16)v.z;
        xb[i + 3] = (bf16)v.w;
        return;
    }
    t -= 8192;
    __shared__ float tile[32][33];
    const float* in; bf16* out; int R, C;
    if (t < 1024)      {            in = Wqa;  out = WfT;                      R = 2048; C = 512;  }
    else if (t < 2176) { t -= 1024; in = Wkva; out = WfT + (size_t)512 * 2048; R = 2048; C = 576;  }
    else if (t < 3712) { t -= 2176; in = Wqb;  out = WqbT;                     R = 512;  C = 3072; }
    else if (t < 5760) { t -= 3712; in = Wkvb; out = WkvbT;                    R = 512;  C = 4096; }
    else               { t -= 5760; in = Wout; out = WoutT;                    R = 2048; C = 2048; }
    int tilesX = (C + 31) >> 5;
    int bx = (t % tilesX) * 32, by = (t / tilesX) * 32;
    int tx = threadIdx.x & 31, ty = threadIdx.x >> 5;
    for (int i = 0; i < 32; i += 8) {
        int r = by + ty + i, c = bx + tx;
        tile[ty + i][tx] = (r < R && c < C) ? in[(size_t)r * C + c] : 0.f;
    }
    __syncthreads();
    for (int i = 0; i < 32; i += 8) {
        int c = bx + ty + i, r = by + tx;
        if (c < C && r < R) out[(size_t)c * R + r] = (bf16)tile[tx][ty + i];
    }
}

// ===========================================================================
// GEMM core body (m97 recipe)
// ===========================================================================
#define GEMM_BODY(Aptr, LDA, Bptr, LDB, KK, BNIDX)                              \
    __shared__ bf16 As[128 * 32];                                               \
    __shared__ bf16 Bs[128 * 32];                                               \
    const int tid  = threadIdx.x;                                               \
    const int wave = tid >> 6, lane = tid & 63;                                 \
    const int quad = lane >> 4, l16 = lane & 15;                                \
    const int bm = blockIdx.x * 128, bn = (BNIDX) * 128;                        \
    const int wm = (wave >> 1) * 64, wn = (wave & 1) * 64;                      \
    const int srow = lane >> 2, scol = (lane & 3) * 8;                          \
    f32x4 acc[4][4];                                                            \
    for (int i = 0; i < 4; i++)                                                 \
        for (int j = 0; j < 4; j++)                                             \
            acc[i][j] = (f32x4){0.f, 0.f, 0.f, 0.f};                            \
    for (int k0 = 0; k0 < (KK); k0 += 32) {                                     \
        _Pragma("unroll")                                                       \
        for (int s2 = 0; s2 < 2; s2++) {                                        \
            const int seg = wave * 2 + s2;                                      \
            const bf16* ga = (Aptr) + (size_t)(bm + seg * 16 + srow) * (LDA) + k0 + scol; \
            const bf16* gb = (Bptr) + (size_t)(bn + seg * 16 + srow) * (LDB) + k0 + scol; \
            __builtin_amdgcn_global_load_lds(                                   \
                (const __attribute__((address_space(1))) void*)ga,              \
                (__attribute__((address_space(3))) void*)&As[seg * 512], 16, 0, 0); \
            __builtin_amdgcn_global_load_lds(                                   \
                (const __attribute__((address_space(1))) void*)gb,              \
                (__attribute__((address_space(3))) void*)&Bs[seg * 512], 16, 0, 0); \
        }                                                                       \
        __syncthreads();                                                        \
        bf16x8 af[4], bfv[4];                                                   \
        for (int mi = 0; mi < 4; mi++)                                          \
            af[mi] = *(const bf16x8*)&As[(wm + mi * 16 + l16) * 32 + quad * 8]; \
        for (int ni = 0; ni < 4; ni++)                                          \
            bfv[ni] = *(const bf16x8*)&Bs[(wn + ni * 16 + l16) * 32 + quad * 8];\
        for (int mi = 0; mi < 4; mi++)                                          \
            for (int ni = 0; ni < 4; ni++)                                      \
                acc[mi][ni] = __builtin_amdgcn_mfma_f32_16x16x32_bf16(          \
                    af[mi], bfv[ni], acc[mi][ni], 0, 0, 0);                     \
        __syncthreads();                                                        \
    }

// ---------------------------------------------------------------------------
// Generic GEMM with plain epilogue (guards on N)
// ---------------------------------------------------------------------------
template <typename OutT>
__global__ __launch_bounds__(256) void gemm_bf16(
    const bf16* __restrict__ A, int lda,
    const bf16* __restrict__ Bt, int ldb,
    OutT* __restrict__ C, int ldc,
    int N, int K)
{
    GEMM_BODY(A, lda, Bt, ldb, K, blockIdx.y)
    for (int mi = 0; mi < 4; mi++)
        for (int ni = 0; ni < 4; ni++) {
            int col = bn + wn + ni * 16 + l16;
            if (col >= N) continue;
            int row0 = bm + wm + mi * 16 + quad * 4;
            for (int r = 0; r < 4; r++)
                C[(size_t)(row0 + r) * ldc + col] = (OutT)acc[mi][ni][r];
        }
}

// ---------------------------------------------------------------------------
// GEMM2+GEMM4 merged (one launch, grid 32 x 56):
//  by<24: q = t1 @ Wqb -> qf, ALL columns raw * QSCALE2 (rope in rope_vt)
//  else : kv = ckv @ Wkvb -> k_nope into kf, v into kvv
// ROUND 7 body (VERIFIED, no spill): pure-store isQ epilogue, same shape as
// the never-spilling isKV branch. Do not reintroduce trig here (3 spills).
// ---------------------------------------------------------------------------
__global__ __launch_bounds__(256) void gemm_qkv(
    const bf16* __restrict__ tc,
    const bf16* __restrict__ WqbT, const bf16* __restrict__ WkvbT,
    bf16* __restrict__ qf, bf16* __restrict__ kf, bf16* __restrict__ kvv)
{
    const int byAll = blockIdx.y;
    const bool isQ = byAll < 24;
    const bf16* A  = isQ ? tc : tc + 512;
    const bf16* Bt = isQ ? WqbT : WkvbT;
    const int bnIdx = isQ ? byAll : byAll - 24;
    GEMM_BODY(A, 1152, Bt, 512, 512, bnIdx)
    if (isQ) {
        for (int mi = 0; mi < 4; mi++)
            for (int ni = 0; ni < 4; ni++) {
                int col0 = bn + wn + ni * 16;
                int h  = col0 / 192;
                int d  = col0 - h * 192 + l16;   // 16-col tile never crosses a head
                for (int r = 0; r < 4; r++) {
                    int row = bm + wm + mi * 16 + quad * 4 + r;
                    int b = row >> 11, n = row & 2047;
                    qf[(((size_t)(b * HEADS + h)) * SEQ + n) * QHEAD + d] =
                        (bf16)(acc[mi][ni][r] * QSCALE2);
                }
            }
    } else {
        for (int mi = 0; mi < 4; mi++)
            for (int ni = 0; ni < 4; ni++) {
                int col0 = bn + wn + ni * 16;
                int h  = col0 >> 8;
                int d0 = col0 & 255;
                int d  = d0 + l16;
                for (int r = 0; r < 4; r++) {
                    int row = bm + wm + mi * 16 + quad * 4 + r;
                    int b = row >> 11, n = row & 2047;
                    bf16 v = (bf16)acc[mi][ni][r];
                    if (d0 < 128)
                        kf[(((size_t)(b * HEADS + h)) * SEQ + n) * QHEAD + d] = v;
                    else
                        kvv[(size_t)row * 2048 + h * 128 + (d - 128)] = v;
                }
            }
    }
}

// ---------------------------------------------------------------------------
// rope_vt merged, 3 tile ranges (ROUND 7 body, verified):
//  t < 8192  : V transpose (kvv -> vT)
//  t < 9216  : k_pe RoPE broadcast into kf (HW-trans sincos)
//  t < 11264 : q RoPE, IN-PLACE on qf[...,128:192]
// ---------------------------------------------------------------------------
__global__ __launch_bounds__(256) void rope_vt(
    const bf16* __restrict__ tc, const bf16* __restrict__ kvv,
    bf16* __restrict__ kf, bf16* __restrict__ vT, bf16* __restrict__ qf)
{
    int t = blockIdx.x;
    if (t < 8192) {
        __shared__ bf16 tile[32][33];
        int bh = t >> 8, rest = t & 255;
        int dv0 = (rest >> 6) * 32, nt0 = (rest & 63) * 32;
        int b = bh >> 4, h = bh & 15;
        int tx = threadIdx.x & 31, ty = threadIdx.x >> 5;
        for (int i = 0; i < 32; i += 8) {
            int n = nt0 + ty + i;
            tile[ty + i][tx] = kvv[((size_t)(b * SEQ + n)) * 2048 + h * 128 + dv0 + tx];
        }
        __syncthreads();
        for (int i = 0; i < 32; i += 8) {
            int dv = dv0 + ty + i;
            vT[((size_t)bh * 128 + dv) * SEQ + nt0 + tx] = tile[tx][ty + i];
        }
    } else if (t < 9216) {
        int gid = (t - 8192) * 256 + threadIdx.x;
        int row = gid >> 6, j = gid & 63;
        int b = row >> 11, n = row & 2047;
        int i = j >> 1;
        float x1 = (float)tc[(size_t)row * 1152 + 1024 + 2 * i];
        float x2 = (float)tc[(size_t)row * 1152 + 1024 + 2 * i + 1];
        float trev = __builtin_amdgcn_exp2f(-(float)i * L2B32) * INV2PI;
        float sn, cs;
        rope_sincos((float)n, trev, sn, cs);
        bf16 rv = (bf16)((j & 1) ? (x1 * sn + x2 * cs) : (x1 * cs - x2 * sn));
        for (int h = 0; h < HEADS; h++)
            kf[(((size_t)(b * HEADS + h)) * SEQ + n) * QHEAD + 128 + j] = rv;
    } else {
        // q RoPE in-place: 32bh x 2048n x 64d space, 8 bf16 per thread
        int gid = (t - 9216) * 256 + threadIdx.x;
        int base = gid * 8;                    // flat index in q_pe space
        int bh  = base >> 17;                  // / (2048*64)
        int rem = base & 131071;
        int n   = rem >> 6;
        int dd  = rem & 63;                    // multiple of 8
        bf16* p = qf + ((size_t)bh * SEQ + n) * QHEAD + 128 + dd;
        bf16x8 v = *(const bf16x8*)p;
        bf16x8 o;
#pragma unroll
        for (int k = 0; k < 4; k++) {
            int i = (dd >> 1) + k;
            float trev = __builtin_amdgcn_exp2f(-(float)i * L2B32) * INV2PI;
            float sn, cs;
            rope_sincos((float)n, trev, sn, cs);
            float x1 = (float)v[2 * k], x2 = (float)v[2 * k + 1];
            o[2 * k]     = (bf16)(x1 * cs - x2 * sn);
            o[2 * k + 1] = (bf16)(x1 * sn + x2 * cs);
        }
        *(bf16x8*)p = o;
    }
}

// ---------------------------------------------------------------------------
// Flash attention, causal, FIXED-SHIFT softmax (no running max / no rescale).
// ROUND 8: DROP Vt LDS STAGING -- V has zero intra-block temporal reuse
// (fresh tile per kt) and is L2/L3-resident (FETCH_SIZE 40 MB total); LDS
// staging only bought 4x cross-wave reuse at the price of 18.4 KB LDS.
// PV now reads V fragments directly from vT (per-lane bf16x8, L2-hit).
// LDS 53248 -> 34816 B => 4 blocks/CU (was 3); VGPR drops (~16 freed).
// K keeps LDS staging + the verified scalarized T14 prefetch (K has real
// 4x cross-wave reuse). T5 setprio retained.
// Tripwire: dur >= 87us or WRITE_SIZE > 100 MB -> revert to round-7 body.
// ---------------------------------------------------------------------------
__global__ __launch_bounds__(256, 2) void attn_fa(
    const bf16* __restrict__ qf, const bf16* __restrict__ kf,
    const bf16* __restrict__ vT, bf16* __restrict__ attn_out)
{
    __shared__ bf16 Ks[64][200];
    __shared__ bf16 Ps[4][16][72];

    const int bid = blockIdx.x;
    const int xcd = bid & 7, j = bid >> 3;     // j = 0..127
    const int qt = 31 - (j >> 2);              // heavy first
    const int bh = xcd + 8 * (j & 3);          // 4 bh per XCD
    const int b = bh >> 4, h = bh & 15;
    const int tid  = threadIdx.x;
    const int wave = tid >> 6, lane = tid & 63;
    const int quad = lane >> 4, l16 = lane & 15;

    bf16x8 aq[6];
    {
        const bf16* qbase = qf + ((size_t)bh * SEQ + qt * 64 + wave * 16 + l16) * QHEAD;
        for (int ks = 0; ks < 6; ks++)
            aq[ks] = *(const bf16x8*)(qbase + ks * 32 + quad * 8);
    }
    f32x4 o[8];
    for (int i = 0; i < 8; i++) o[i] = (f32x4){0.f, 0.f, 0.f, 0.f};
    float lp[4] = {0.f, 0.f, 0.f, 0.f};   // per-lane partial row sums

    // V fragment base for this lane: row nv*16+l16, col kt*64+ks2*32+quad*8
    const bf16* vrow = vT + ((size_t)bh * 128 + l16) * SEQ + quad * 8;

    // --- fully scalarized K staging state (NO arrays: rule #20) -------------
    const bf16 *kp0, *kp1, *kp2, *kp3, *kp4, *kp5;
    bf16 *kd0, *kd1, *kd2, *kd3, *kd4, *kd5;
#define KINIT(I)                                                                \
    { int c = tid + I * 256; int r = c / 24, col = (c - r * 24) * 8;            \
      kp##I = kf + ((size_t)bh * SEQ + r) * QHEAD + col;                        \
      kd##I = &Ks[r][col]; }
    KINIT(0) KINIT(1) KINIT(2) KINIT(3) KINIT(4) KINIT(5)
#undef KINIT

    uint4 kb0 = *(const uint4*)kp0, kb1 = *(const uint4*)kp1,
          kb2 = *(const uint4*)kp2, kb3 = *(const uint4*)kp3,
          kb4 = *(const uint4*)kp4, kb5 = *(const uint4*)kp5;

    for (int kt = 0; kt <= qt; kt++) {
        __syncthreads();                       // prev iter's Ks consumers done
        *(uint4*)kd0 = kb0; *(uint4*)kd1 = kb1; *(uint4*)kd2 = kb2;
        *(uint4*)kd3 = kb3; *(uint4*)kd4 = kb4; *(uint4*)kd5 = kb5;
        __syncthreads();                       // Ks visible

        if (kt < qt) {                         // prefetch kt+1; latency hides
            kp0 += 64 * QHEAD; kb0 = *(const uint4*)kp0;
            kp1 += 64 * QHEAD; kb1 = *(const uint4*)kp1;
            kp2 += 64 * QHEAD; kb2 = *(const uint4*)kp2;
            kp3 += 64 * QHEAD; kb3 = *(const uint4*)kp3;
            kp4 += 64 * QHEAD; kb4 = *(const uint4*)kp4;
            kp5 += 64 * QHEAD; kb5 = *(const uint4*)kp5;
        }

        f32x4 sacc[4];
        for (int nt = 0; nt < 4; nt++) sacc[nt] = (f32x4){0.f, 0.f, 0.f, 0.f};
        __builtin_amdgcn_s_setprio(1);
        for (int ks = 0; ks < 6; ks++)
            for (int nt = 0; nt < 4; nt++) {
                bf16x8 bk = *(const bf16x8*)&Ks[nt * 16 + l16][ks * 32 + quad * 8];
                sacc[nt] = __builtin_amdgcn_mfma_f32_16x16x32_bf16(aq[ks], bk, sacc[nt], 0, 0, 0);
            }
        __builtin_amdgcn_s_setprio(0);

        // p = 2^(sacc - CSHIFT); causal zeroing only on the diagonal tile
        const bool diag = (kt == qt);
#pragma unroll
        for (int r = 0; r < 4; r++) {
            const int qrow = wave * 16 + quad * 4 + r;
#pragma unroll
            for (int nt = 0; nt < 4; nt++) {
                float p;
                if (diag && (nt * 16 + l16 > qrow)) p = 0.f;
                else p = __builtin_amdgcn_exp2f(sacc[nt][r] - CSHIFT);
                lp[r] += p;
                Ps[wave][quad * 4 + r][nt * 16 + l16] = (bf16)p;
            }
        }
        __builtin_amdgcn_sched_barrier(0);   // Ps wave-private; pin order

        // PV: V fragments straight from L2-resident vT (no LDS round-trip)
        __builtin_amdgcn_s_setprio(1);
        for (int ks2 = 0; ks2 < 2; ks2++) {
            bf16x8 ap = *(const bf16x8*)&Ps[wave][l16][ks2 * 32 + quad * 8];
            const bf16* vcol = vrow + kt * 64 + ks2 * 32;
            for (int nv = 0; nv < 8; nv++) {
                bf16x8 bv = *(const bf16x8*)(vcol + (size_t)(nv * 16) * SEQ);
                o[nv] = __builtin_amdgcn_mfma_f32_16x16x32_bf16(ap, bv, o[nv], 0, 0, 0);
            }
        }
        __builtin_amdgcn_s_setprio(0);
    }

    // single cross-lane reduction of the row sums (4 independent chains)
#pragma unroll
    for (int r = 0; r < 4; r++) {
        lp[r] += __shfl_xor(lp[r], 8);
        lp[r] += __shfl_xor(lp[r], 4);
        lp[r] += __shfl_xor(lp[r], 2);
        lp[r] += __shfl_xor(lp[r], 1);
    }

    for (int r = 0; r < 4; r++) {
        float inv = 1.f / lp[r];
        size_t row = (size_t)b * SEQ + qt * 64 + wave * 16 + quad * 4 + r;
        for (int nv = 0; nv < 8; nv++)
            attn_out[row * 2048 + h * 128 + nv * 16 + l16] = (bf16)(o[nv][r] * inv);
    }
}

// ---------------------------------------------------------------------------
extern "C" void kernel_launch(void* const* d_in, const int* in_sizes, int n_in,
                              void* d_out, int out_size, void* d_ws, size_t ws_size,
                              hipStream_t stream)
{
    const float* x    = (const float*)d_in[0];
    const float* Wqa  = (const float*)d_in[1];
    const float* Wqb  = (const float*)d_in[2];
    const float* Wkva = (const float*)d_in[3];
    const float* Wkvb = (const float*)d_in[4];
    const float* Wout = (const float*)d_in[5];
    float* out = (float*)d_out;

    char* ws = (char*)d_ws;
    size_t off = 0;
    auto alloc = [&](size_t elems) { char* p = ws + off; off += elems * sizeof(bf16); return (bf16*)p; };
    bf16* xb    = alloc((size_t)ROWS * 2048);   // reused as `attn` later
    bf16* WfT   = alloc((size_t)1152 * 2048);   // [WqaT(512) ; WkvaT(576) ; pad]
    bf16* WqbT  = alloc((size_t)3072 * 512);
    bf16* WkvbT = alloc((size_t)4096 * 512);
    bf16* WoutT = alloc((size_t)2048 * 2048);
    bf16* tc    = alloc((size_t)ROWS * 1152);   // [t1(512) | ckv(512) | k_pe(64) | pad]
    bf16* kvv   = alloc((size_t)ROWS * 2048);   // v only, [row][h*128+dv]
    bf16* vT    = alloc((size_t)32 * 128 * SEQ);
    bf16* qf    = alloc((size_t)32 * SEQ * QHEAD);
    bf16* kf    = alloc((size_t)32 * SEQ * QHEAD);
    bf16* attn  = xb;                           // alias: xb dead after gemm13
    if (off > ws_size) return;                  // distinguishable failure

    dim3 blk(256);

    // convert + all weight transposes, one launch
    prep<<<dim3(18048), blk, 0, stream>>>(x, Wqa, Wqb, Wkva, Wkvb, Wout,
                                          xb, WfT, WqbT, WkvbT, WoutT);

    // GEMM1+3 fused (plain epilogue): tc[:,0:1088] = x @ [Wqa|Wkva], K=2048
    gemm_bf16<bf16><<<dim3(32, 9), blk, 0, stream>>>(xb, 2048, WfT, 2048, tc, 1152, 1088, 2048);

    // GEMM2 (raw q -> qf) + GEMM4 (k_nope->kf, v->kvv), one launch
    gemm_qkv<<<dim3(32, 56), blk, 0, stream>>>(tc, WqbT, WkvbT, qf, kf, kvv);

    // V transpose + k_pe RoPE broadcast + q RoPE (in-place on qf), one launch
    rope_vt<<<dim3(11264), blk, 0, stream>>>(tc, kvv, kf, vT, qf);

    // flash attention: 1024 blocks, one qt each, heavy-first, XCD-stable bh
    attn_fa<<<dim3(1024), blk, 0, stream>>>(qf, kf, vT, attn);

    // GEMM5: out = attn @ Wout   [4096,2048] K=2048  (fp32 output)
    gemm_bf16<float><<<dim3(32, 16), blk, 0, stream>>>(attn, 2048, WoutT, 2048, out, 2048, 2048, 2048);
}

// Round 9
// 389.411 us; speedup vs baseline: 1.1651x; 1.1651x over previous
//
#include <hip/hip_runtime.h>
#include <math.h>

typedef __bf16 bf16;
typedef __bf16 bf16x8 __attribute__((ext_vector_type(8)));
typedef float f32x4 __attribute__((ext_vector_type(4)));

#define HEADS 16
#define QHEAD 192
#define NB 2
#define SEQ 2048
#define ROWS (NB * SEQ)
/* q pre-scale = log2(e)/sqrt(192): scores arrive in exp2 domain */
#define QSCALE2 0.10411754584f
/* fixed softmax shift: p = 2^(sacc - CSHIFT) = exp(s_nat - 8) */
#define CSHIFT 11.5415603272f
/* log2(10000)/32 — rope theta_i = 2^(-i * L2B32) */
#define L2B32 0.41524101186092029f
/* 1/(2*pi) — radians -> revolutions for v_sin/v_cos */
#define INV2PI 0.15915494309189535f

// fast RoPE sincos: theta_rev premultiplied by 1/2pi; v_sin/v_cos take
// revolutions, range-reduced with fract. Angle error ~2e-4 rad << bf16
// rounding. Verified rounds 5-8 (absmax 0.0156).
__device__ __forceinline__ void rope_sincos(float n, float theta_rev,
                                            float& sn, float& cs)
{
    float rev = n * theta_rev;
    rev -= floorf(rev);
    sn = __builtin_amdgcn_sinf(rev);
    cs = __builtin_amdgcn_cosf(rev);
}

// ---------------------------------------------------------------------------
// prep: fp32->bf16 convert of x (tiles 0..8191) + all 5 weight transposes
// ---------------------------------------------------------------------------
__global__ __launch_bounds__(256) void prep(
    const float* __restrict__ x,
    const float* __restrict__ Wqa, const float* __restrict__ Wqb,
    const float* __restrict__ Wkva, const float* __restrict__ Wkvb,
    const float* __restrict__ Wout,
    bf16* __restrict__ xb,
    bf16* __restrict__ WfT, bf16* __restrict__ WqbT,
    bf16* __restrict__ WkvbT, bf16* __restrict__ WoutT)
{
    int t = blockIdx.x;
    if (t < 8192) {
        size_t i = ((size_t)t * 256 + threadIdx.x) * 4;
        float4 v = *(const float4*)(x + i);
        xb[i]     = (bf16)v.x;
        xb[i + 1] = (bf16)v.y;
        xb[i + 2] = (bf16)v.z;
        xb[i + 3] = (bf16)v.w;
        return;
    }
    t -= 8192;
    __shared__ float tile[32][33];
    const float* in; bf16* out; int R, C;
    if (t < 1024)      {            in = Wqa;  out = WfT;                      R = 2048; C = 512;  }
    else if (t < 2176) { t -= 1024; in = Wkva; out = WfT + (size_t)512 * 2048; R = 2048; C = 576;  }
    else if (t < 3712) { t -= 2176; in = Wqb;  out = WqbT;                     R = 512;  C = 3072; }
    else if (t < 5760) { t -= 3712; in = Wkvb; out = WkvbT;                    R = 512;  C = 4096; }
    else               { t -= 5760; in = Wout; out = WoutT;                    R = 2048; C = 2048; }
    int tilesX = (C + 31) >> 5;
    int bx = (t % tilesX) * 32, by = (t / tilesX) * 32;
    int tx = threadIdx.x & 31, ty = threadIdx.x >> 5;
    for (int i = 0; i < 32; i += 8) {
        int r = by + ty + i, c = bx + tx;
        tile[ty + i][tx] = (r < R && c < C) ? in[(size_t)r * C + c] : 0.f;
    }
    __syncthreads();
    for (int i = 0; i < 32; i += 8) {
        int c = bx + ty + i, r = by + tx;
        if (c < C && r < R) out[(size_t)c * R + r] = (bf16)tile[tx][ty + i];
    }
}

// ===========================================================================
// GEMM core body (m97 recipe)
// ===========================================================================
#define GEMM_BODY(Aptr, LDA, Bptr, LDB, KK, BNIDX)                              \
    __shared__ bf16 As[128 * 32];                                               \
    __shared__ bf16 Bs[128 * 32];                                               \
    const int tid  = threadIdx.x;                                               \
    const int wave = tid >> 6, lane = tid & 63;                                 \
    const int quad = lane >> 4, l16 = lane & 15;                                \
    const int bm = blockIdx.x * 128, bn = (BNIDX) * 128;                        \
    const int wm = (wave >> 1) * 64, wn = (wave & 1) * 64;                      \
    const int srow = lane >> 2, scol = (lane & 3) * 8;                          \
    f32x4 acc[4][4];                                                            \
    for (int i = 0; i < 4; i++)                                                 \
        for (int j = 0; j < 4; j++)                                             \
            acc[i][j] = (f32x4){0.f, 0.f, 0.f, 0.f};                            \
    for (int k0 = 0; k0 < (KK); k0 += 32) {                                     \
        _Pragma("unroll")                                                       \
        for (int s2 = 0; s2 < 2; s2++) {                                        \
            const int seg = wave * 2 + s2;                                      \
            const bf16* ga = (Aptr) + (size_t)(bm + seg * 16 + srow) * (LDA) + k0 + scol; \
            const bf16* gb = (Bptr) + (size_t)(bn + seg * 16 + srow) * (LDB) + k0 + scol; \
            __builtin_amdgcn_global_load_lds(                                   \
                (const __attribute__((address_space(1))) void*)ga,              \
                (__attribute__((address_space(3))) void*)&As[seg * 512], 16, 0, 0); \
            __builtin_amdgcn_global_load_lds(                                   \
                (const __attribute__((address_space(1))) void*)gb,              \
                (__attribute__((address_space(3))) void*)&Bs[seg * 512], 16, 0, 0); \
        }                                                                       \
        __syncthreads();                                                        \
        bf16x8 af[4], bfv[4];                                                   \
        for (int mi = 0; mi < 4; mi++)                                          \
            af[mi] = *(const bf16x8*)&As[(wm + mi * 16 + l16) * 32 + quad * 8]; \
        for (int ni = 0; ni < 4; ni++)                                          \
            bfv[ni] = *(const bf16x8*)&Bs[(wn + ni * 16 + l16) * 32 + quad * 8];\
        for (int mi = 0; mi < 4; mi++)                                          \
            for (int ni = 0; ni < 4; ni++)                                      \
                acc[mi][ni] = __builtin_amdgcn_mfma_f32_16x16x32_bf16(          \
                    af[mi], bfv[ni], acc[mi][ni], 0, 0, 0);                     \
        __syncthreads();                                                        \
    }

// ---------------------------------------------------------------------------
// Generic GEMM with plain epilogue (guards on N)
// ---------------------------------------------------------------------------
template <typename OutT>
__global__ __launch_bounds__(256) void gemm_bf16(
    const bf16* __restrict__ A, int lda,
    const bf16* __restrict__ Bt, int ldb,
    OutT* __restrict__ C, int ldc,
    int N, int K)
{
    GEMM_BODY(A, lda, Bt, ldb, K, blockIdx.y)
    for (int mi = 0; mi < 4; mi++)
        for (int ni = 0; ni < 4; ni++) {
            int col = bn + wn + ni * 16 + l16;
            if (col >= N) continue;
            int row0 = bm + wm + mi * 16 + quad * 4;
            for (int r = 0; r < 4; r++)
                C[(size_t)(row0 + r) * ldc + col] = (OutT)acc[mi][ni][r];
        }
}

// ---------------------------------------------------------------------------
// GEMM2+GEMM4 merged (one launch, grid 32 x 56):
//  by<24: q = t1 @ Wqb -> qf, ALL columns raw * QSCALE2 (rope in rope_vt)
//  else : kv = ckv @ Wkvb -> k_nope into kf, v into kvv
// ROUND 7 body (VERIFIED, no spill): pure-store isQ epilogue, same shape as
// the never-spilling isKV branch. Do not reintroduce trig here (3 spills).
// ---------------------------------------------------------------------------
__global__ __launch_bounds__(256) void gemm_qkv(
    const bf16* __restrict__ tc,
    const bf16* __restrict__ WqbT, const bf16* __restrict__ WkvbT,
    bf16* __restrict__ qf, bf16* __restrict__ kf, bf16* __restrict__ kvv)
{
    const int byAll = blockIdx.y;
    const bool isQ = byAll < 24;
    const bf16* A  = isQ ? tc : tc + 512;
    const bf16* Bt = isQ ? WqbT : WkvbT;
    const int bnIdx = isQ ? byAll : byAll - 24;
    GEMM_BODY(A, 1152, Bt, 512, 512, bnIdx)
    if (isQ) {
        for (int mi = 0; mi < 4; mi++)
            for (int ni = 0; ni < 4; ni++) {
                int col0 = bn + wn + ni * 16;
                int h  = col0 / 192;
                int d  = col0 - h * 192 + l16;   // 16-col tile never crosses a head
                for (int r = 0; r < 4; r++) {
                    int row = bm + wm + mi * 16 + quad * 4 + r;
                    int b = row >> 11, n = row & 2047;
                    qf[(((size_t)(b * HEADS + h)) * SEQ + n) * QHEAD + d] =
                        (bf16)(acc[mi][ni][r] * QSCALE2);
                }
            }
    } else {
        for (int mi = 0; mi < 4; mi++)
            for (int ni = 0; ni < 4; ni++) {
                int col0 = bn + wn + ni * 16;
                int h  = col0 >> 8;
                int d0 = col0 & 255;
                int d  = d0 + l16;
                for (int r = 0; r < 4; r++) {
                    int row = bm + wm + mi * 16 + quad * 4 + r;
                    int b = row >> 11, n = row & 2047;
                    bf16 v = (bf16)acc[mi][ni][r];
                    if (d0 < 128)
                        kf[(((size_t)(b * HEADS + h)) * SEQ + n) * QHEAD + d] = v;
                    else
                        kvv[(size_t)row * 2048 + h * 128 + (d - 128)] = v;
                }
            }
    }
}

// ---------------------------------------------------------------------------
// rope_vt merged, 3 tile ranges (ROUND 7 body, verified):
//  t < 8192  : V transpose (kvv -> vT)
//  t < 9216  : k_pe RoPE broadcast into kf (HW-trans sincos)
//  t < 11264 : q RoPE, IN-PLACE on qf[...,128:192]
// ---------------------------------------------------------------------------
__global__ __launch_bounds__(256) void rope_vt(
    const bf16* __restrict__ tc, const bf16* __restrict__ kvv,
    bf16* __restrict__ kf, bf16* __restrict__ vT, bf16* __restrict__ qf)
{
    int t = blockIdx.x;
    if (t < 8192) {
        __shared__ bf16 tile[32][33];
        int bh = t >> 8, rest = t & 255;
        int dv0 = (rest >> 6) * 32, nt0 = (rest & 63) * 32;
        int b = bh >> 4, h = bh & 15;
        int tx = threadIdx.x & 31, ty = threadIdx.x >> 5;
        for (int i = 0; i < 32; i += 8) {
            int n = nt0 + ty + i;
            tile[ty + i][tx] = kvv[((size_t)(b * SEQ + n)) * 2048 + h * 128 + dv0 + tx];
        }
        __syncthreads();
        for (int i = 0; i < 32; i += 8) {
            int dv = dv0 + ty + i;
            vT[((size_t)bh * 128 + dv) * SEQ + nt0 + tx] = tile[tx][ty + i];
        }
    } else if (t < 9216) {
        int gid = (t - 8192) * 256 + threadIdx.x;
        int row = gid >> 6, j = gid & 63;
        int b = row >> 11, n = row & 2047;
        int i = j >> 1;
        float x1 = (float)tc[(size_t)row * 1152 + 1024 + 2 * i];
        float x2 = (float)tc[(size_t)row * 1152 + 1024 + 2 * i + 1];
        float trev = __builtin_amdgcn_exp2f(-(float)i * L2B32) * INV2PI;
        float sn, cs;
        rope_sincos((float)n, trev, sn, cs);
        bf16 rv = (bf16)((j & 1) ? (x1 * sn + x2 * cs) : (x1 * cs - x2 * sn));
        for (int h = 0; h < HEADS; h++)
            kf[(((size_t)(b * HEADS + h)) * SEQ + n) * QHEAD + 128 + j] = rv;
    } else {
        // q RoPE in-place: 32bh x 2048n x 64d space, 8 bf16 per thread
        int gid = (t - 9216) * 256 + threadIdx.x;
        int base = gid * 8;                    // flat index in q_pe space
        int bh  = base >> 17;                  // / (2048*64)
        int rem = base & 131071;
        int n   = rem >> 6;
        int dd  = rem & 63;                    // multiple of 8
        bf16* p = qf + ((size_t)bh * SEQ + n) * QHEAD + 128 + dd;
        bf16x8 v = *(const bf16x8*)p;
        bf16x8 o;
#pragma unroll
        for (int k = 0; k < 4; k++) {
            int i = (dd >> 1) + k;
            float trev = __builtin_amdgcn_exp2f(-(float)i * L2B32) * INV2PI;
            float sn, cs;
            rope_sincos((float)n, trev, sn, cs);
            float x1 = (float)v[2 * k], x2 = (float)v[2 * k + 1];
            o[2 * k]     = (bf16)(x1 * cs - x2 * sn);
            o[2 * k + 1] = (bf16)(x1 * sn + x2 * cs);
        }
        *(bf16x8*)p = o;
    }
}

// ---------------------------------------------------------------------------
// Flash attention, causal, FIXED-SHIFT softmax.
// ROUND 9 (QBLK=128): round-7 counters imply LDS-pipe-bound (~830 LDS
// cy/wave/iter vs 200 MFMA cy; model reproduces the 87us). Round 8 (L2-direct
// V) reverted per tripwire: removed LDS traffic but exposed VMEM latency
// (MfmaUtil 20->10). This round raises MFMA-per-LDS-byte instead: each block
// owns a 128-row Q tile; each wave holds TWO q-row-sets (w*16, w*16+64); every
// bk/bv fragment is loaded from LDS once and feeds two MFMAs. LDS layout,
// K/V staging, scalarized T14 prefetch: identical to round 7. Ps buffer
// reused sequentially by the two halves (wave-private, in-order DS ops).
// LDS cy/MFMA 20.8 -> 12.9; barriers per unit work halved. Grid 512.
// Causality: half0 active kt<ktmax (diag at ktmax-1); half1 diag at ktmax.
// Tripwire: WRITE_SIZE>100MB or dur>=87us -> revert to round-7 attn forever.
// ---------------------------------------------------------------------------
__global__ __launch_bounds__(256, 2) void attn_fa(
    const bf16* __restrict__ qf, const bf16* __restrict__ kf,
    const bf16* __restrict__ vT, bf16* __restrict__ attn_out)
{
    __shared__ bf16 Ks[64][200];
    __shared__ bf16 Vt[128][72];
    __shared__ bf16 Ps[4][16][72];

    const int bid = blockIdx.x;
    const int xcd = bid & 7, j = bid >> 3;     // j = 0..63
    const int qtp = 15 - (j >> 2);             // 128-row q-tile, heavy first
    const int bh = xcd + 8 * (j & 3);          // 4 bh per XCD
    const int b = bh >> 4, h = bh & 15;
    const int tid  = threadIdx.x;
    const int wave = tid >> 6, lane = tid & 63;
    const int quad = lane >> 4, l16 = lane & 15;

    bf16x8 aq0[6], aq1[6];
    {
        const bf16* qb0 = qf + ((size_t)bh * SEQ + qtp * 128 + wave * 16 + l16) * QHEAD;
        const bf16* qb1 = qb0 + (size_t)64 * QHEAD;
        for (int ks = 0; ks < 6; ks++) {
            aq0[ks] = *(const bf16x8*)(qb0 + ks * 32 + quad * 8);
            aq1[ks] = *(const bf16x8*)(qb1 + ks * 32 + quad * 8);
        }
    }
    f32x4 o0[8], o1[8];
    for (int i = 0; i < 8; i++) {
        o0[i] = (f32x4){0.f, 0.f, 0.f, 0.f};
        o1[i] = (f32x4){0.f, 0.f, 0.f, 0.f};
    }
    float lp0[4] = {0.f, 0.f, 0.f, 0.f};
    float lp1[4] = {0.f, 0.f, 0.f, 0.f};

    // --- fully scalarized K/V staging state (NO arrays: rule #20) -----------
    const bf16 *kp0, *kp1, *kp2, *kp3, *kp4, *kp5;
    bf16 *kd0, *kd1, *kd2, *kd3, *kd4, *kd5;
    const bf16 *vp0, *vp1, *vp2, *vp3;
    bf16 *vd0, *vd1, *vd2, *vd3;
#define KINIT(I)                                                                \
    { int c = tid + I * 256; int r = c / 24, col = (c - r * 24) * 8;            \
      kp##I = kf + ((size_t)bh * SEQ + r) * QHEAD + col;                        \
      kd##I = &Ks[r][col]; }
#define VINIT(I)                                                                \
    { int c = tid + I * 256; int dv = c >> 3, g = c & 7;                        \
      vp##I = vT + ((size_t)bh * 128 + dv) * SEQ + g * 8;                       \
      vd##I = &Vt[dv][g * 8]; }
    KINIT(0) KINIT(1) KINIT(2) KINIT(3) KINIT(4) KINIT(5)
    VINIT(0) VINIT(1) VINIT(2) VINIT(3)
#undef KINIT
#undef VINIT

    uint4 kb0 = *(const uint4*)kp0, kb1 = *(const uint4*)kp1,
          kb2 = *(const uint4*)kp2, kb3 = *(const uint4*)kp3,
          kb4 = *(const uint4*)kp4, kb5 = *(const uint4*)kp5;
    uint4 vb0 = *(const uint4*)vp0, vb1 = *(const uint4*)vp1,
          vb2 = *(const uint4*)vp2, vb3 = *(const uint4*)vp3;

    const int ktmax = 2 * qtp + 1;             // last k-tile (diag of half1)

    for (int kt = 0; kt <= ktmax; kt++) {
        __syncthreads();                       // prev iter's LDS consumers done
        *(uint4*)kd0 = kb0; *(uint4*)kd1 = kb1; *(uint4*)kd2 = kb2;
        *(uint4*)kd3 = kb3; *(uint4*)kd4 = kb4; *(uint4*)kd5 = kb5;
        *(uint4*)vd0 = vb0; *(uint4*)vd1 = vb1;
        *(uint4*)vd2 = vb2; *(uint4*)vd3 = vb3;
        __syncthreads();                       // LDS visible

        if (kt < ktmax) {                      // prefetch kt+1; latency hides
            kp0 += 64 * QHEAD; kb0 = *(const uint4*)kp0;
            kp1 += 64 * QHEAD; kb1 = *(const uint4*)kp1;
            kp2 += 64 * QHEAD; kb2 = *(const uint4*)kp2;
            kp3 += 64 * QHEAD; kb3 = *(const uint4*)kp3;
            kp4 += 64 * QHEAD; kb4 = *(const uint4*)kp4;
            kp5 += 64 * QHEAD; kb5 = *(const uint4*)kp5;
            vp0 += 64; vb0 = *(const uint4*)vp0;
            vp1 += 64; vb1 = *(const uint4*)vp1;
            vp2 += 64; vb2 = *(const uint4*)vp2;
            vp3 += 64; vb3 = *(const uint4*)vp3;
        }

        // QK^T both halves: each bk fragment read ONCE, used twice
        f32x4 s0[4], s1[4];
        for (int nt = 0; nt < 4; nt++) {
            s0[nt] = (f32x4){0.f, 0.f, 0.f, 0.f};
            s1[nt] = (f32x4){0.f, 0.f, 0.f, 0.f};
        }
        __builtin_amdgcn_s_setprio(1);
        for (int ks = 0; ks < 6; ks++)
            for (int nt = 0; nt < 4; nt++) {
                bf16x8 bk = *(const bf16x8*)&Ks[nt * 16 + l16][ks * 32 + quad * 8];
                s0[nt] = __builtin_amdgcn_mfma_f32_16x16x32_bf16(aq0[ks], bk, s0[nt], 0, 0, 0);
                s1[nt] = __builtin_amdgcn_mfma_f32_16x16x32_bf16(aq1[ks], bk, s1[nt], 0, 0, 0);
            }
        __builtin_amdgcn_s_setprio(0);

        // ---- half0 (rows qtp*128 + wave*16 + ...) ----
        if (kt < ktmax) {
            const bool diag0 = (kt == ktmax - 1);
#pragma unroll
            for (int r = 0; r < 4; r++) {
                const int qrow = wave * 16 + quad * 4 + r;
#pragma unroll
                for (int nt = 0; nt < 4; nt++) {
                    float p;
                    if (diag0 && (nt * 16 + l16 > qrow)) p = 0.f;
                    else p = __builtin_amdgcn_exp2f(s0[nt][r] - CSHIFT);
                    lp0[r] += p;
                    Ps[wave][quad * 4 + r][nt * 16 + l16] = (bf16)p;
                }
            }
            __builtin_amdgcn_sched_barrier(0);
            __builtin_amdgcn_s_setprio(1);
            for (int ks2 = 0; ks2 < 2; ks2++) {
                bf16x8 ap = *(const bf16x8*)&Ps[wave][l16][ks2 * 32 + quad * 8];
                for (int nv = 0; nv < 8; nv++) {
                    bf16x8 bv = *(const bf16x8*)&Vt[nv * 16 + l16][ks2 * 32 + quad * 8];
                    o0[nv] = __builtin_amdgcn_mfma_f32_16x16x32_bf16(ap, bv, o0[nv], 0, 0, 0);
                }
            }
            __builtin_amdgcn_s_setprio(0);
            __builtin_amdgcn_sched_barrier(0);   // PV0 Ps-reads before half1 Ps-writes
        }

        // ---- half1 (rows qtp*128 + 64 + wave*16 + ...) ----
        {
            const bool diag1 = (kt == ktmax);
#pragma unroll
            for (int r = 0; r < 4; r++) {
                const int qrow = wave * 16 + quad * 4 + r;
#pragma unroll
                for (int nt = 0; nt < 4; nt++) {
                    float p;
                    if (diag1 && (nt * 16 + l16 > qrow)) p = 0.f;
                    else p = __builtin_amdgcn_exp2f(s1[nt][r] - CSHIFT);
                    lp1[r] += p;
                    Ps[wave][quad * 4 + r][nt * 16 + l16] = (bf16)p;
                }
            }
            __builtin_amdgcn_sched_barrier(0);
            __builtin_amdgcn_s_setprio(1);
            for (int ks2 = 0; ks2 < 2; ks2++) {
                bf16x8 ap = *(const bf16x8*)&Ps[wave][l16][ks2 * 32 + quad * 8];
                for (int nv = 0; nv < 8; nv++) {
                    bf16x8 bv = *(const bf16x8*)&Vt[nv * 16 + l16][ks2 * 32 + quad * 8];
                    o1[nv] = __builtin_amdgcn_mfma_f32_16x16x32_bf16(ap, bv, o1[nv], 0, 0, 0);
                }
            }
            __builtin_amdgcn_s_setprio(0);
        }
    }

    // cross-lane reduction of the row sums (both halves)
#pragma unroll
    for (int r = 0; r < 4; r++) {
        lp0[r] += __shfl_xor(lp0[r], 8);
        lp0[r] += __shfl_xor(lp0[r], 4);
        lp0[r] += __shfl_xor(lp0[r], 2);
        lp0[r] += __shfl_xor(lp0[r], 1);
        lp1[r] += __shfl_xor(lp1[r], 8);
        lp1[r] += __shfl_xor(lp1[r], 4);
        lp1[r] += __shfl_xor(lp1[r], 2);
        lp1[r] += __shfl_xor(lp1[r], 1);
    }

    for (int r = 0; r < 4; r++) {
        float inv0 = 1.f / lp0[r];
        float inv1 = 1.f / lp1[r];
        size_t row0 = (size_t)b * SEQ + qtp * 128 + wave * 16 + quad * 4 + r;
        size_t row1 = row0 + 64;
        for (int nv = 0; nv < 8; nv++) {
            attn_out[row0 * 2048 + h * 128 + nv * 16 + l16] = (bf16)(o0[nv][r] * inv0);
            attn_out[row1 * 2048 + h * 128 + nv * 16 + l16] = (bf16)(o1[nv][r] * inv1);
        }
    }
}

// ---------------------------------------------------------------------------
extern "C" void kernel_launch(void* const* d_in, const int* in_sizes, int n_in,
                              void* d_out, int out_size, void* d_ws, size_t ws_size,
                              hipStream_t stream)
{
    const float* x    = (const float*)d_in[0];
    const float* Wqa  = (const float*)d_in[1];
    const float* Wqb  = (const float*)d_in[2];
    const float* Wkva = (const float*)d_in[3];
    const float* Wkvb = (const float*)d_in[4];
    const float* Wout = (const float*)d_in[5];
    float* out = (float*)d_out;

    char* ws = (char*)d_ws;
    size_t off = 0;
    auto alloc = [&](size_t elems) { char* p = ws + off; off += elems * sizeof(bf16); return (bf16*)p; };
    bf16* xb    = alloc((size_t)ROWS * 2048);   // reused as `attn` later
    bf16* WfT   = alloc((size_t)1152 * 2048);   // [WqaT(512) ; WkvaT(576) ; pad]
    bf16* WqbT  = alloc((size_t)3072 * 512);
    bf16* WkvbT = alloc((size_t)4096 * 512);
    bf16* WoutT = alloc((size_t)2048 * 2048);
    bf16* tc    = alloc((size_t)ROWS * 1152);   // [t1(512) | ckv(512) | k_pe(64) | pad]
    bf16* kvv   = alloc((size_t)ROWS * 2048);   // v only, [row][h*128+dv]
    bf16* vT    = alloc((size_t)32 * 128 * SEQ);
    bf16* qf    = alloc((size_t)32 * SEQ * QHEAD);
    bf16* kf    = alloc((size_t)32 * SEQ * QHEAD);
    bf16* attn  = xb;                           // alias: xb dead after gemm13
    if (off > ws_size) return;                  // distinguishable failure

    dim3 blk(256);

    // convert + all weight transposes, one launch
    prep<<<dim3(18048), blk, 0, stream>>>(x, Wqa, Wqb, Wkva, Wkvb, Wout,
                                          xb, WfT, WqbT, WkvbT, WoutT);

    // GEMM1+3 fused (plain epilogue): tc[:,0:1088] = x @ [Wqa|Wkva], K=2048
    gemm_bf16<bf16><<<dim3(32, 9), blk, 0, stream>>>(xb, 2048, WfT, 2048, tc, 1152, 1088, 2048);

    // GEMM2 (raw q -> qf) + GEMM4 (k_nope->kf, v->kvv), one launch
    gemm_qkv<<<dim3(32, 56), blk, 0, stream>>>(tc, WqbT, WkvbT, qf, kf, kvv);

    // V transpose + k_pe RoPE broadcast + q RoPE (in-place on qf), one launch
    rope_vt<<<dim3(11264), blk, 0, stream>>>(tc, kvv, kf, vT, qf);

    // flash attention: 512 blocks, one 128-row q-tile each, heavy-first
    attn_fa<<<dim3(512), blk, 0, stream>>>(qf, kf, vT, attn);

    // GEMM5: out = attn @ Wout   [4096,2048] K=2048  (fp32 output)
    gemm_bf16<float><<<dim3(32, 16), blk, 0, stream>>>(attn, 2048, WoutT, 2048, out, 2048, 2048, 2048);
}

// Round 10
// 359.343 us; speedup vs baseline: 1.2626x; 1.0837x over previous
//
#include <hip/hip_runtime.h>
#include <math.h>

typedef __bf16 bf16;
typedef __bf16 bf16x4 __attribute__((ext_vector_type(4)));
typedef __bf16 bf16x8 __attribute__((ext_vector_type(8)));
typedef float f32x4 __attribute__((ext_vector_type(4)));

#define HEADS 16
#define QHEAD 192
#define NB 2
#define SEQ 2048
#define ROWS (NB * SEQ)
/* q pre-scale = log2(e)/sqrt(192): scores arrive in exp2 domain */
#define QSCALE2 0.10411754584f
/* fixed softmax shift: p = 2^(sacc - CSHIFT) = exp(s_nat - 8) */
#define CSHIFT 11.5415603272f
/* log2(10000)/32 — rope theta_i = 2^(-i * L2B32) */
#define L2B32 0.41524101186092029f
/* 1/(2*pi) — radians -> revolutions for v_sin/v_cos */
#define INV2PI 0.15915494309189535f

// fast RoPE sincos: theta_rev premultiplied by 1/2pi; v_sin/v_cos take
// revolutions, range-reduced with fract. Verified rounds 5-9 (absmax 0.0156).
__device__ __forceinline__ void rope_sincos(float n, float theta_rev,
                                            float& sn, float& cs)
{
    float rev = n * theta_rev;
    rev -= floorf(rev);
    sn = __builtin_amdgcn_sinf(rev);
    cs = __builtin_amdgcn_cosf(rev);
}

// ---------------------------------------------------------------------------
// prep: fp32->bf16 convert of x (tiles 0..8191) + all 5 weight transposes
// ---------------------------------------------------------------------------
__global__ __launch_bounds__(256) void prep(
    const float* __restrict__ x,
    const float* __restrict__ Wqa, const float* __restrict__ Wqb,
    const float* __restrict__ Wkva, const float* __restrict__ Wkvb,
    const float* __restrict__ Wout,
    bf16* __restrict__ xb,
    bf16* __restrict__ WfT, bf16* __restrict__ WqbT,
    bf16* __restrict__ WkvbT, bf16* __restrict__ WoutT)
{
    int t = blockIdx.x;
    if (t < 8192) {
        size_t i = ((size_t)t * 256 + threadIdx.x) * 4;
        float4 v = *(const float4*)(x + i);
        xb[i]     = (bf16)v.x;
        xb[i + 1] = (bf16)v.y;
        xb[i + 2] = (bf16)v.z;
        xb[i + 3] = (bf16)v.w;
        return;
    }
    t -= 8192;
    __shared__ float tile[32][33];
    const float* in; bf16* out; int R, C;
    if (t < 1024)      {            in = Wqa;  out = WfT;                      R = 2048; C = 512;  }
    else if (t < 2176) { t -= 1024; in = Wkva; out = WfT + (size_t)512 * 2048; R = 2048; C = 576;  }
    else if (t < 3712) { t -= 2176; in = Wqb;  out = WqbT;                     R = 512;  C = 3072; }
    else if (t < 5760) { t -= 3712; in = Wkvb; out = WkvbT;                    R = 512;  C = 4096; }
    else               { t -= 5760; in = Wout; out = WoutT;                    R = 2048; C = 2048; }
    int tilesX = (C + 31) >> 5;
    int bx = (t % tilesX) * 32, by = (t / tilesX) * 32;
    int tx = threadIdx.x & 31, ty = threadIdx.x >> 5;
    for (int i = 0; i < 32; i += 8) {
        int r = by + ty + i, c = bx + tx;
        tile[ty + i][tx] = (r < R && c < C) ? in[(size_t)r * C + c] : 0.f;
    }
    __syncthreads();
    for (int i = 0; i < 32; i += 8) {
        int c = bx + ty + i, r = by + tx;
        if (c < C && r < R) out[(size_t)c * R + r] = (bf16)tile[tx][ty + i];
    }
}

// ===========================================================================
// GEMM core body (m97 recipe)
// ===========================================================================
#define GEMM_BODY(Aptr, LDA, Bptr, LDB, KK, BNIDX)                              \
    __shared__ bf16 As[128 * 32];                                               \
    __shared__ bf16 Bs[128 * 32];                                               \
    const int tid  = threadIdx.x;                                               \
    const int wave = tid >> 6, lane = tid & 63;                                 \
    const int quad = lane >> 4, l16 = lane & 15;                                \
    const int bm = blockIdx.x * 128, bn = (BNIDX) * 128;                        \
    const int wm = (wave >> 1) * 64, wn = (wave & 1) * 64;                      \
    const int srow = lane >> 2, scol = (lane & 3) * 8;                          \
    f32x4 acc[4][4];                                                            \
    for (int i = 0; i < 4; i++)                                                 \
        for (int j = 0; j < 4; j++)                                             \
            acc[i][j] = (f32x4){0.f, 0.f, 0.f, 0.f};                            \
    for (int k0 = 0; k0 < (KK); k0 += 32) {                                     \
        _Pragma("unroll")                                                       \
        for (int s2 = 0; s2 < 2; s2++) {                                        \
            const int seg = wave * 2 + s2;                                      \
            const bf16* ga = (Aptr) + (size_t)(bm + seg * 16 + srow) * (LDA) + k0 + scol; \
            const bf16* gb = (Bptr) + (size_t)(bn + seg * 16 + srow) * (LDB) + k0 + scol; \
            __builtin_amdgcn_global_load_lds(                                   \
                (const __attribute__((address_space(1))) void*)ga,              \
                (__attribute__((address_space(3))) void*)&As[seg * 512], 16, 0, 0); \
            __builtin_amdgcn_global_load_lds(                                   \
                (const __attribute__((address_space(1))) void*)gb,              \
                (__attribute__((address_space(3))) void*)&Bs[seg * 512], 16, 0, 0); \
        }                                                                       \
        __syncthreads();                                                        \
        bf16x8 af[4], bfv[4];                                                   \
        for (int mi = 0; mi < 4; mi++)                                          \
            af[mi] = *(const bf16x8*)&As[(wm + mi * 16 + l16) * 32 + quad * 8]; \
        for (int ni = 0; ni < 4; ni++)                                          \
            bfv[ni] = *(const bf16x8*)&Bs[(wn + ni * 16 + l16) * 32 + quad * 8];\
        for (int mi = 0; mi < 4; mi++)                                          \
            for (int ni = 0; ni < 4; ni++)                                      \
                acc[mi][ni] = __builtin_amdgcn_mfma_f32_16x16x32_bf16(          \
                    af[mi], bfv[ni], acc[mi][ni], 0, 0, 0);                     \
        __syncthreads();                                                        \
    }

// ---------------------------------------------------------------------------
// Generic GEMM with plain epilogue (guards on N)
// ---------------------------------------------------------------------------
template <typename OutT>
__global__ __launch_bounds__(256) void gemm_bf16(
    const bf16* __restrict__ A, int lda,
    const bf16* __restrict__ Bt, int ldb,
    OutT* __restrict__ C, int ldc,
    int N, int K)
{
    GEMM_BODY(A, lda, Bt, ldb, K, blockIdx.y)
    for (int mi = 0; mi < 4; mi++)
        for (int ni = 0; ni < 4; ni++) {
            int col = bn + wn + ni * 16 + l16;
            if (col >= N) continue;
            int row0 = bm + wm + mi * 16 + quad * 4;
            for (int r = 0; r < 4; r++)
                C[(size_t)(row0 + r) * ldc + col] = (OutT)acc[mi][ni][r];
        }
}

// ---------------------------------------------------------------------------
// GEMM2+GEMM4 merged (one launch, grid 32 x 56):
//  by<24: q = t1 @ Wqb -> qf, ALL columns raw * QSCALE2 (rope in rope_vt)
//  else : kv = ckv @ Wkvb -> k_nope into kf, v DIRECT-TRANSPOSED into vT
// ROUND 10: v-epilogue packs each thread's 4 consecutive-n acc values into
// one bf16x4 (8B) store at vT[(bh*128+dv)*SEQ + n0] -- the transpose falls
// out of the fragment layout for free. Eliminates kvv (16 MB) and rope_vt's
// 8192-tile LDS transpose pass (32 MB traffic). Epilogue remains pure
// stores+casts (the no-spill class of rounds 4/7; no trig, no loads).
// ---------------------------------------------------------------------------
__global__ __launch_bounds__(256) void gemm_qkv(
    const bf16* __restrict__ tc,
    const bf16* __restrict__ WqbT, const bf16* __restrict__ WkvbT,
    bf16* __restrict__ qf, bf16* __restrict__ kf, bf16* __restrict__ vT)
{
    const int byAll = blockIdx.y;
    const bool isQ = byAll < 24;
    const bf16* A  = isQ ? tc : tc + 512;
    const bf16* Bt = isQ ? WqbT : WkvbT;
    const int bnIdx = isQ ? byAll : byAll - 24;
    GEMM_BODY(A, 1152, Bt, 512, 512, bnIdx)
    if (isQ) {
        for (int mi = 0; mi < 4; mi++)
            for (int ni = 0; ni < 4; ni++) {
                int col0 = bn + wn + ni * 16;
                int h  = col0 / 192;
                int d  = col0 - h * 192 + l16;   // 16-col tile never crosses a head
                for (int r = 0; r < 4; r++) {
                    int row = bm + wm + mi * 16 + quad * 4 + r;
                    int b = row >> 11, n = row & 2047;
                    qf[(((size_t)(b * HEADS + h)) * SEQ + n) * QHEAD + d] =
                        (bf16)(acc[mi][ni][r] * QSCALE2);
                }
            }
    } else {
        for (int mi = 0; mi < 4; mi++)
            for (int ni = 0; ni < 4; ni++) {
                int col0 = bn + wn + ni * 16;
                int h  = col0 >> 8;
                int d0 = col0 & 255;
                if (d0 < 128) {
                    int d = d0 + l16;
                    for (int r = 0; r < 4; r++) {
                        int row = bm + wm + mi * 16 + quad * 4 + r;
                        int b = row >> 11, n = row & 2047;
                        kf[(((size_t)(b * HEADS + h)) * SEQ + n) * QHEAD + d] =
                            (bf16)acc[mi][ni][r];
                    }
                } else {
                    // direct transposed V write: 4 consecutive n per thread
                    int dv = d0 - 128 + l16;
                    int row0 = bm + wm + mi * 16 + quad * 4;
                    int b = row0 >> 11, n0 = row0 & 2047;
                    bf16x4 pk;
                    pk[0] = (bf16)acc[mi][ni][0];
                    pk[1] = (bf16)acc[mi][ni][1];
                    pk[2] = (bf16)acc[mi][ni][2];
                    pk[3] = (bf16)acc[mi][ni][3];
                    *(bf16x4*)&vT[((size_t)((b * HEADS + h) * 128 + dv)) * SEQ + n0] = pk;
                }
            }
    }
}

// ---------------------------------------------------------------------------
// rope_vt, 2 tile ranges (V transpose moved into gemm_qkv epilogue):
//  t < 1024 : k_pe RoPE broadcast into kf (HW-trans sincos)
//  t < 3072 : q RoPE, IN-PLACE on qf[...,128:192]
// ---------------------------------------------------------------------------
__global__ __launch_bounds__(256) void rope_vt(
    const bf16* __restrict__ tc,
    bf16* __restrict__ kf, bf16* __restrict__ qf)
{
    int t = blockIdx.x;
    if (t < 1024) {
        int gid = t * 256 + threadIdx.x;
        int row = gid >> 6, j = gid & 63;
        int b = row >> 11, n = row & 2047;
        int i = j >> 1;
        float x1 = (float)tc[(size_t)row * 1152 + 1024 + 2 * i];
        float x2 = (float)tc[(size_t)row * 1152 + 1024 + 2 * i + 1];
        float trev = __builtin_amdgcn_exp2f(-(float)i * L2B32) * INV2PI;
        float sn, cs;
        rope_sincos((float)n, trev, sn, cs);
        bf16 rv = (bf16)((j & 1) ? (x1 * sn + x2 * cs) : (x1 * cs - x2 * sn));
        for (int h = 0; h < HEADS; h++)
            kf[(((size_t)(b * HEADS + h)) * SEQ + n) * QHEAD + 128 + j] = rv;
    } else {
        // q RoPE in-place: 32bh x 2048n x 64d space, 8 bf16 per thread
        int gid = (t - 1024) * 256 + threadIdx.x;
        int base = gid * 8;                    // flat index in q_pe space
        int bh  = base >> 17;                  // / (2048*64)
        int rem = base & 131071;
        int n   = rem >> 6;
        int dd  = rem & 63;                    // multiple of 8
        bf16* p = qf + ((size_t)bh * SEQ + n) * QHEAD + 128 + dd;
        bf16x8 v = *(const bf16x8*)p;
        bf16x8 o;
#pragma unroll
        for (int k = 0; k < 4; k++) {
            int i = (dd >> 1) + k;
            float trev = __builtin_amdgcn_exp2f(-(float)i * L2B32) * INV2PI;
            float sn, cs;
            rope_sincos((float)n, trev, sn, cs);
            float x1 = (float)v[2 * k], x2 = (float)v[2 * k + 1];
            o[2 * k]     = (bf16)(x1 * cs - x2 * sn);
            o[2 * k + 1] = (bf16)(x1 * sn + x2 * cs);
        }
        *(bf16x8*)p = o;
    }
}

// ---------------------------------------------------------------------------
// Flash attention, causal, FIXED-SHIFT softmax (no running max / no rescale).
// ROUND 7 body, FROZEN: T14 register-prefetch with fully SCALARIZED staging
// (rule #20). Three structural variants lost to it (L2-direct V: 172us;
// QBLK=128: 105us; this: 87us). Do not touch.
// ---------------------------------------------------------------------------
__global__ __launch_bounds__(256, 2) void attn_fa(
    const bf16* __restrict__ qf, const bf16* __restrict__ kf,
    const bf16* __restrict__ vT, bf16* __restrict__ attn_out)
{
    __shared__ bf16 Ks[64][200];
    __shared__ bf16 Vt[128][72];
    __shared__ bf16 Ps[4][16][72];

    const int bid = blockIdx.x;
    const int xcd = bid & 7, j = bid >> 3;     // j = 0..127
    const int qt = 31 - (j >> 2);              // heavy first
    const int bh = xcd + 8 * (j & 3);          // 4 bh per XCD
    const int b = bh >> 4, h = bh & 15;
    const int tid  = threadIdx.x;
    const int wave = tid >> 6, lane = tid & 63;
    const int quad = lane >> 4, l16 = lane & 15;

    bf16x8 aq[6];
    {
        const bf16* qbase = qf + ((size_t)bh * SEQ + qt * 64 + wave * 16 + l16) * QHEAD;
        for (int ks = 0; ks < 6; ks++)
            aq[ks] = *(const bf16x8*)(qbase + ks * 32 + quad * 8);
    }
    f32x4 o[8];
    for (int i = 0; i < 8; i++) o[i] = (f32x4){0.f, 0.f, 0.f, 0.f};
    float lp[4] = {0.f, 0.f, 0.f, 0.f};   // per-lane partial row sums

    // --- fully scalarized staging state (NO arrays: rule #20) ---------------
    const bf16 *kp0, *kp1, *kp2, *kp3, *kp4, *kp5;
    bf16 *kd0, *kd1, *kd2, *kd3, *kd4, *kd5;
    const bf16 *vp0, *vp1, *vp2, *vp3;
    bf16 *vd0, *vd1, *vd2, *vd3;
#define KINIT(I)                                                                \
    { int c = tid + I * 256; int r = c / 24, col = (c - r * 24) * 8;            \
      kp##I = kf + ((size_t)bh * SEQ + r) * QHEAD + col;                        \
      kd##I = &Ks[r][col]; }
#define VINIT(I)                                                                \
    { int c = tid + I * 256; int dv = c >> 3, g = c & 7;                        \
      vp##I = vT + ((size_t)bh * 128 + dv) * SEQ + g * 8;                       \
      vd##I = &Vt[dv][g * 8]; }
    KINIT(0) KINIT(1) KINIT(2) KINIT(3) KINIT(4) KINIT(5)
    VINIT(0) VINIT(1) VINIT(2) VINIT(3)
#undef KINIT
#undef VINIT

    uint4 kb0 = *(const uint4*)kp0, kb1 = *(const uint4*)kp1,
          kb2 = *(const uint4*)kp2, kb3 = *(const uint4*)kp3,
          kb4 = *(const uint4*)kp4, kb5 = *(const uint4*)kp5;
    uint4 vb0 = *(const uint4*)vp0, vb1 = *(const uint4*)vp1,
          vb2 = *(const uint4*)vp2, vb3 = *(const uint4*)vp3;

    for (int kt = 0; kt <= qt; kt++) {
        __syncthreads();                       // prev iter's LDS consumers done
        *(uint4*)kd0 = kb0; *(uint4*)kd1 = kb1; *(uint4*)kd2 = kb2;
        *(uint4*)kd3 = kb3; *(uint4*)kd4 = kb4; *(uint4*)kd5 = kb5;
        *(uint4*)vd0 = vb0; *(uint4*)vd1 = vb1;
        *(uint4*)vd2 = vb2; *(uint4*)vd3 = vb3;
        __syncthreads();                       // LDS visible

        if (kt < qt) {                         // prefetch kt+1; latency hides
            kp0 += 64 * QHEAD; kb0 = *(const uint4*)kp0;
            kp1 += 64 * QHEAD; kb1 = *(const uint4*)kp1;
            kp2 += 64 * QHEAD; kb2 = *(const uint4*)kp2;
            kp3 += 64 * QHEAD; kb3 = *(const uint4*)kp3;
            kp4 += 64 * QHEAD; kb4 = *(const uint4*)kp4;
            kp5 += 64 * QHEAD; kb5 = *(const uint4*)kp5;
            vp0 += 64; vb0 = *(const uint4*)vp0;
            vp1 += 64; vb1 = *(const uint4*)vp1;
            vp2 += 64; vb2 = *(const uint4*)vp2;
            vp3 += 64; vb3 = *(const uint4*)vp3;
        }

        f32x4 sacc[4];
        for (int nt = 0; nt < 4; nt++) sacc[nt] = (f32x4){0.f, 0.f, 0.f, 0.f};
        __builtin_amdgcn_s_setprio(1);
        for (int ks = 0; ks < 6; ks++)
            for (int nt = 0; nt < 4; nt++) {
                bf16x8 bk = *(const bf16x8*)&Ks[nt * 16 + l16][ks * 32 + quad * 8];
                sacc[nt] = __builtin_amdgcn_mfma_f32_16x16x32_bf16(aq[ks], bk, sacc[nt], 0, 0, 0);
            }
        __builtin_amdgcn_s_setprio(0);

        // p = 2^(sacc - CSHIFT); causal zeroing only on the diagonal tile
        const bool diag = (kt == qt);
#pragma unroll
        for (int r = 0; r < 4; r++) {
            const int qrow = wave * 16 + quad * 4 + r;
#pragma unroll
            for (int nt = 0; nt < 4; nt++) {
                float p;
                if (diag && (nt * 16 + l16 > qrow)) p = 0.f;
                else p = __builtin_amdgcn_exp2f(sacc[nt][r] - CSHIFT);
                lp[r] += p;
                Ps[wave][quad * 4 + r][nt * 16 + l16] = (bf16)p;
            }
        }
        __builtin_amdgcn_sched_barrier(0);   // Ps wave-private; pin order

        __builtin_amdgcn_s_setprio(1);
        for (int ks2 = 0; ks2 < 2; ks2++) {
            bf16x8 ap = *(const bf16x8*)&Ps[wave][l16][ks2 * 32 + quad * 8];
            for (int nv = 0; nv < 8; nv++) {
                bf16x8 bv = *(const bf16x8*)&Vt[nv * 16 + l16][ks2 * 32 + quad * 8];
                o[nv] = __builtin_amdgcn_mfma_f32_16x16x32_bf16(ap, bv, o[nv], 0, 0, 0);
            }
        }
        __builtin_amdgcn_s_setprio(0);
    }

    // single cross-lane reduction of the row sums (4 independent chains)
#pragma unroll
    for (int r = 0; r < 4; r++) {
        lp[r] += __shfl_xor(lp[r], 8);
        lp[r] += __shfl_xor(lp[r], 4);
        lp[r] += __shfl_xor(lp[r], 2);
        lp[r] += __shfl_xor(lp[r], 1);
    }

    for (int r = 0; r < 4; r++) {
        float inv = 1.f / lp[r];
        size_t row = (size_t)b * SEQ + qt * 64 + wave * 16 + quad * 4 + r;
        for (int nv = 0; nv < 8; nv++)
            attn_out[row * 2048 + h * 128 + nv * 16 + l16] = (bf16)(o[nv][r] * inv);
    }
}

// ---------------------------------------------------------------------------
extern "C" void kernel_launch(void* const* d_in, const int* in_sizes, int n_in,
                              void* d_out, int out_size, void* d_ws, size_t ws_size,
                              hipStream_t stream)
{
    const float* x    = (const float*)d_in[0];
    const float* Wqa  = (const float*)d_in[1];
    const float* Wqb  = (const float*)d_in[2];
    const float* Wkva = (const float*)d_in[3];
    const float* Wkvb = (const float*)d_in[4];
    const float* Wout = (const float*)d_in[5];
    float* out = (float*)d_out;

    char* ws = (char*)d_ws;
    size_t off = 0;
    auto alloc = [&](size_t elems) { char* p = ws + off; off += elems * sizeof(bf16); return (bf16*)p; };
    bf16* xb    = alloc((size_t)ROWS * 2048);   // reused as `attn` later
    bf16* WfT   = alloc((size_t)1152 * 2048);   // [WqaT(512) ; WkvaT(576) ; pad]
    bf16* WqbT  = alloc((size_t)3072 * 512);
    bf16* WkvbT = alloc((size_t)4096 * 512);
    bf16* WoutT = alloc((size_t)2048 * 2048);
    bf16* tc    = alloc((size_t)ROWS * 1152);   // [t1(512) | ckv(512) | k_pe(64) | pad]
    bf16* vT    = alloc((size_t)32 * 128 * SEQ);
    bf16* qf    = alloc((size_t)32 * SEQ * QHEAD);
    bf16* kf    = alloc((size_t)32 * SEQ * QHEAD);
    bf16* attn  = xb;                           // alias: xb dead after gemm13
    if (off > ws_size) return;                  // distinguishable failure

    dim3 blk(256);

    // convert + all weight transposes, one launch
    prep<<<dim3(18048), blk, 0, stream>>>(x, Wqa, Wqb, Wkva, Wkvb, Wout,
                                          xb, WfT, WqbT, WkvbT, WoutT);

    // GEMM1+3 fused (plain epilogue): tc[:,0:1088] = x @ [Wqa|Wkva], K=2048
    gemm_bf16<bf16><<<dim3(32, 9), blk, 0, stream>>>(xb, 2048, WfT, 2048, tc, 1152, 1088, 2048);

    // GEMM2 (raw q -> qf) + GEMM4 (k_nope->kf, v direct-transposed -> vT)
    gemm_qkv<<<dim3(32, 56), blk, 0, stream>>>(tc, WqbT, WkvbT, qf, kf, vT);

    // k_pe RoPE broadcast + q RoPE (in-place on qf), one launch
    rope_vt<<<dim3(3072), blk, 0, stream>>>(tc, kf, qf);

    // flash attention: 1024 blocks, one qt each, heavy-first, XCD-stable bh
    attn_fa<<<dim3(1024), blk, 0, stream>>>(qf, kf, vT, attn);

    // GEMM5: out = attn @ Wout   [4096,2048] K=2048  (fp32 output)
    gemm_bf16<float><<<dim3(32, 16), blk, 0, stream>>>(attn, 2048, WoutT, 2048, out, 2048, 2048, 2048);
}

// Round 11
// 348.159 us; speedup vs baseline: 1.3031x; 1.0321x over previous
//
#include <hip/hip_runtime.h>
#include <math.h>

typedef __bf16 bf16;
typedef __bf16 bf16x4 __attribute__((ext_vector_type(4)));
typedef __bf16 bf16x8 __attribute__((ext_vector_type(8)));
typedef float f32x4 __attribute__((ext_vector_type(4)));

#define HEADS 16
#define QHEAD 192
#define NB 2
#define SEQ 2048
#define ROWS (NB * SEQ)
/* q pre-scale = log2(e)/sqrt(192): scores arrive in exp2 domain */
#define QSCALE2 0.10411754584f
/* fixed softmax shift: p = 2^(sacc - CSHIFT) = exp(s_nat - 8) */
#define CSHIFT 11.5415603272f
/* log2(10000)/32 — rope theta_i = 2^(-i * L2B32) */
#define L2B32 0.41524101186092029f
/* 1/(2*pi) — radians -> revolutions for v_sin/v_cos */
#define INV2PI 0.15915494309189535f

// fast RoPE sincos: theta_rev premultiplied by 1/2pi; v_sin/v_cos take
// revolutions, range-reduced with fract. Verified rounds 5-10 (absmax 0.0156).
__device__ __forceinline__ void rope_sincos(float n, float theta_rev,
                                            float& sn, float& cs)
{
    float rev = n * theta_rev;
    rev -= floorf(rev);
    sn = __builtin_amdgcn_sinf(rev);
    cs = __builtin_amdgcn_cosf(rev);
}

// ---------------------------------------------------------------------------
// prep: fp32->bf16 convert of x (tiles 0..8191) + all 5 weight transposes
// ---------------------------------------------------------------------------
__global__ __launch_bounds__(256) void prep(
    const float* __restrict__ x,
    const float* __restrict__ Wqa, const float* __restrict__ Wqb,
    const float* __restrict__ Wkva, const float* __restrict__ Wkvb,
    const float* __restrict__ Wout,
    bf16* __restrict__ xb,
    bf16* __restrict__ WfT, bf16* __restrict__ WqbT,
    bf16* __restrict__ WkvbT, bf16* __restrict__ WoutT)
{
    int t = blockIdx.x;
    if (t < 8192) {
        size_t i = ((size_t)t * 256 + threadIdx.x) * 4;
        float4 v = *(const float4*)(x + i);
        xb[i]     = (bf16)v.x;
        xb[i + 1] = (bf16)v.y;
        xb[i + 2] = (bf16)v.z;
        xb[i + 3] = (bf16)v.w;
        return;
    }
    t -= 8192;
    __shared__ float tile[32][33];
    const float* in; bf16* out; int R, C;
    if (t < 1024)      {            in = Wqa;  out = WfT;                      R = 2048; C = 512;  }
    else if (t < 2176) { t -= 1024; in = Wkva; out = WfT + (size_t)512 * 2048; R = 2048; C = 576;  }
    else if (t < 3712) { t -= 2176; in = Wqb;  out = WqbT;                     R = 512;  C = 3072; }
    else if (t < 5760) { t -= 3712; in = Wkvb; out = WkvbT;                    R = 512;  C = 4096; }
    else               { t -= 5760; in = Wout; out = WoutT;                    R = 2048; C = 2048; }
    int tilesX = (C + 31) >> 5;
    int bx = (t % tilesX) * 32, by = (t / tilesX) * 32;
    int tx = threadIdx.x & 31, ty = threadIdx.x >> 5;
    for (int i = 0; i < 32; i += 8) {
        int r = by + ty + i, c = bx + tx;
        tile[ty + i][tx] = (r < R && c < C) ? in[(size_t)r * C + c] : 0.f;
    }
    __syncthreads();
    for (int i = 0; i < 32; i += 8) {
        int c = bx + ty + i, r = by + tx;
        if (c < C && r < R) out[(size_t)c * R + r] = (bf16)tile[tx][ty + i];
    }
}

// ===========================================================================
// GEMM core body (m97 recipe), 128x128 tile
// ===========================================================================
#define GEMM_BODY(Aptr, LDA, Bptr, LDB, KK, BNIDX)                              \
    __shared__ bf16 As[128 * 32];                                               \
    __shared__ bf16 Bs[128 * 32];                                               \
    const int tid  = threadIdx.x;                                               \
    const int wave = tid >> 6, lane = tid & 63;                                 \
    const int quad = lane >> 4, l16 = lane & 15;                                \
    const int bm = blockIdx.x * 128, bn = (BNIDX) * 128;                        \
    const int wm = (wave >> 1) * 64, wn = (wave & 1) * 64;                      \
    const int srow = lane >> 2, scol = (lane & 3) * 8;                          \
    f32x4 acc[4][4];                                                            \
    for (int i = 0; i < 4; i++)                                                 \
        for (int j = 0; j < 4; j++)                                             \
            acc[i][j] = (f32x4){0.f, 0.f, 0.f, 0.f};                            \
    for (int k0 = 0; k0 < (KK); k0 += 32) {                                     \
        _Pragma("unroll")                                                       \
        for (int s2 = 0; s2 < 2; s2++) {                                        \
            const int seg = wave * 2 + s2;                                      \
            const bf16* ga = (Aptr) + (size_t)(bm + seg * 16 + srow) * (LDA) + k0 + scol; \
            const bf16* gb = (Bptr) + (size_t)(bn + seg * 16 + srow) * (LDB) + k0 + scol; \
            __builtin_amdgcn_global_load_lds(                                   \
                (const __attribute__((address_space(1))) void*)ga,              \
                (__attribute__((address_space(3))) void*)&As[seg * 512], 16, 0, 0); \
            __builtin_amdgcn_global_load_lds(                                   \
                (const __attribute__((address_space(1))) void*)gb,              \
                (__attribute__((address_space(3))) void*)&Bs[seg * 512], 16, 0, 0); \
        }                                                                       \
        __syncthreads();                                                        \
        bf16x8 af[4], bfv[4];                                                   \
        for (int mi = 0; mi < 4; mi++)                                          \
            af[mi] = *(const bf16x8*)&As[(wm + mi * 16 + l16) * 32 + quad * 8]; \
        for (int ni = 0; ni < 4; ni++)                                          \
            bfv[ni] = *(const bf16x8*)&Bs[(wn + ni * 16 + l16) * 32 + quad * 8];\
        for (int mi = 0; mi < 4; mi++)                                          \
            for (int ni = 0; ni < 4; ni++)                                      \
                acc[mi][ni] = __builtin_amdgcn_mfma_f32_16x16x32_bf16(          \
                    af[mi], bfv[ni], acc[mi][ni], 0, 0, 0);                     \
        __syncthreads();                                                        \
    }

// ---------------------------------------------------------------------------
// Generic GEMM with plain epilogue (guards on N), 128x128
// ---------------------------------------------------------------------------
template <typename OutT>
__global__ __launch_bounds__(256) void gemm_bf16(
    const bf16* __restrict__ A, int lda,
    const bf16* __restrict__ Bt, int ldb,
    OutT* __restrict__ C, int ldc,
    int N, int K)
{
    GEMM_BODY(A, lda, Bt, ldb, K, blockIdx.y)
    for (int mi = 0; mi < 4; mi++)
        for (int ni = 0; ni < 4; ni++) {
            int col = bn + wn + ni * 16 + l16;
            if (col >= N) continue;
            int row0 = bm + wm + mi * 16 + quad * 4;
            for (int r = 0; r < 4; r++)
                C[(size_t)(row0 + r) * ldc + col] = (OutT)acc[mi][ni][r];
        }
}

// ---------------------------------------------------------------------------
// ROUND 11: 128x64-tile GEMM for the occupancy-starved shapes.
// m102 shape curve: rate tracks blocks/CU (1/CU=320TF, 4/CU=833TF). gemm13
// (grid 288 = 1.1/CU) and gemm5 (512 = 2/CU) are latency-starved with the
// 128x128 tile. BN=64 doubles the grid: gemm13 544, gemm5 1024 (4/CU).
// Staging: 12 chunks of 16 rows (8 As + 4 Bs) over 4 waves x 3 slots; the
// As/Bs select is wave-uniform (scalar branch). 2x2 wave grid: each wave
// 64x32 out = acc[4][2], 8 MFMA + 6 ds_read per K-step. LDS 12 KB.
// Epilogue: plain stores (the no-spill class).
// ---------------------------------------------------------------------------
template <typename OutT>
__global__ __launch_bounds__(256) void gemm_n64(
    const bf16* __restrict__ A, int lda,
    const bf16* __restrict__ Bt, int ldb,
    OutT* __restrict__ C, int ldc,
    int N, int K)
{
    __shared__ bf16 As[128 * 32];
    __shared__ bf16 Bs[64 * 32];
    const int tid  = threadIdx.x;
    const int wave = tid >> 6, lane = tid & 63;
    const int quad = lane >> 4, l16 = lane & 15;
    const int bm = blockIdx.x * 128, bn = blockIdx.y * 64;
    const int wm = (wave >> 1) * 64, wn = (wave & 1) * 32;
    const int srow = lane >> 2, scol = (lane & 3) * 8;
    f32x4 acc[4][2];
    for (int i = 0; i < 4; i++)
        for (int j = 0; j < 2; j++)
            acc[i][j] = (f32x4){0.f, 0.f, 0.f, 0.f};
    for (int k0 = 0; k0 < K; k0 += 32) {
#pragma unroll
        for (int s2 = 0; s2 < 3; s2++) {
            const int seg = wave * 3 + s2;         // 0..11, wave-uniform
            if (seg < 8) {                          // As chunk
                const bf16* ga = A + (size_t)(bm + seg * 16 + srow) * lda + k0 + scol;
                __builtin_amdgcn_global_load_lds(
                    (const __attribute__((address_space(1))) void*)ga,
                    (__attribute__((address_space(3))) void*)&As[seg * 512], 16, 0, 0);
            } else {                                // Bs chunk
                const bf16* gb = Bt + (size_t)(bn + (seg - 8) * 16 + srow) * ldb + k0 + scol;
                __builtin_amdgcn_global_load_lds(
                    (const __attribute__((address_space(1))) void*)gb,
                    (__attribute__((address_space(3))) void*)&Bs[(seg - 8) * 512], 16, 0, 0);
            }
        }
        __syncthreads();
        bf16x8 af[4], bfv[2];
        for (int mi = 0; mi < 4; mi++)
            af[mi] = *(const bf16x8*)&As[(wm + mi * 16 + l16) * 32 + quad * 8];
        for (int ni = 0; ni < 2; ni++)
            bfv[ni] = *(const bf16x8*)&Bs[(wn + ni * 16 + l16) * 32 + quad * 8];
        for (int mi = 0; mi < 4; mi++)
            for (int ni = 0; ni < 2; ni++)
                acc[mi][ni] = __builtin_amdgcn_mfma_f32_16x16x32_bf16(
                    af[mi], bfv[ni], acc[mi][ni], 0, 0, 0);
        __syncthreads();
    }
    for (int mi = 0; mi < 4; mi++)
        for (int ni = 0; ni < 2; ni++) {
            int col = bn + wn + ni * 16 + l16;
            if (col >= N) continue;
            int row0 = bm + wm + mi * 16 + quad * 4;
            for (int r = 0; r < 4; r++)
                C[(size_t)(row0 + r) * ldc + col] = (OutT)acc[mi][ni][r];
        }
}

// ---------------------------------------------------------------------------
// GEMM2+GEMM4 merged (one launch, grid 32 x 56):
//  by<24: q = t1 @ Wqb -> qf, ALL columns raw * QSCALE2 (rope in rope_vt)
//  else : kv = ckv @ Wkvb -> k_nope into kf, v DIRECT-TRANSPOSED into vT
// ROUND 10 body (VERIFIED): pure-store epilogues; vT written transposed
// straight from the fragment (bf16x4 pack). No trig here (3 spills).
// ---------------------------------------------------------------------------
__global__ __launch_bounds__(256) void gemm_qkv(
    const bf16* __restrict__ tc,
    const bf16* __restrict__ WqbT, const bf16* __restrict__ WkvbT,
    bf16* __restrict__ qf, bf16* __restrict__ kf, bf16* __restrict__ vT)
{
    const int byAll = blockIdx.y;
    const bool isQ = byAll < 24;
    const bf16* A  = isQ ? tc : tc + 512;
    const bf16* Bt = isQ ? WqbT : WkvbT;
    const int bnIdx = isQ ? byAll : byAll - 24;
    GEMM_BODY(A, 1152, Bt, 512, 512, bnIdx)
    if (isQ) {
        for (int mi = 0; mi < 4; mi++)
            for (int ni = 0; ni < 4; ni++) {
                int col0 = bn + wn + ni * 16;
                int h  = col0 / 192;
                int d  = col0 - h * 192 + l16;   // 16-col tile never crosses a head
                for (int r = 0; r < 4; r++) {
                    int row = bm + wm + mi * 16 + quad * 4 + r;
                    int b = row >> 11, n = row & 2047;
                    qf[(((size_t)(b * HEADS + h)) * SEQ + n) * QHEAD + d] =
                        (bf16)(acc[mi][ni][r] * QSCALE2);
                }
            }
    } else {
        for (int mi = 0; mi < 4; mi++)
            for (int ni = 0; ni < 4; ni++) {
                int col0 = bn + wn + ni * 16;
                int h  = col0 >> 8;
                int d0 = col0 & 255;
                if (d0 < 128) {
                    int d = d0 + l16;
                    for (int r = 0; r < 4; r++) {
                        int row = bm + wm + mi * 16 + quad * 4 + r;
                        int b = row >> 11, n = row & 2047;
                        kf[(((size_t)(b * HEADS + h)) * SEQ + n) * QHEAD + d] =
                            (bf16)acc[mi][ni][r];
                    }
                } else {
                    // direct transposed V write: 4 consecutive n per thread
                    int dv = d0 - 128 + l16;
                    int row0 = bm + wm + mi * 16 + quad * 4;
                    int b = row0 >> 11, n0 = row0 & 2047;
                    bf16x4 pk;
                    pk[0] = (bf16)acc[mi][ni][0];
                    pk[1] = (bf16)acc[mi][ni][1];
                    pk[2] = (bf16)acc[mi][ni][2];
                    pk[3] = (bf16)acc[mi][ni][3];
                    *(bf16x4*)&vT[((size_t)((b * HEADS + h) * 128 + dv)) * SEQ + n0] = pk;
                }
            }
    }
}

// ---------------------------------------------------------------------------
// rope_vt, 2 tile ranges:
//  t < 1024 : k_pe RoPE broadcast into kf (HW-trans sincos)
//  t < 3072 : q RoPE, IN-PLACE on qf[...,128:192]
// ---------------------------------------------------------------------------
__global__ __launch_bounds__(256) void rope_vt(
    const bf16* __restrict__ tc,
    bf16* __restrict__ kf, bf16* __restrict__ qf)
{
    int t = blockIdx.x;
    if (t < 1024) {
        int gid = t * 256 + threadIdx.x;
        int row = gid >> 6, j = gid & 63;
        int b = row >> 11, n = row & 2047;
        int i = j >> 1;
        float x1 = (float)tc[(size_t)row * 1152 + 1024 + 2 * i];
        float x2 = (float)tc[(size_t)row * 1152 + 1024 + 2 * i + 1];
        float trev = __builtin_amdgcn_exp2f(-(float)i * L2B32) * INV2PI;
        float sn, cs;
        rope_sincos((float)n, trev, sn, cs);
        bf16 rv = (bf16)((j & 1) ? (x1 * sn + x2 * cs) : (x1 * cs - x2 * sn));
        for (int h = 0; h < HEADS; h++)
            kf[(((size_t)(b * HEADS + h)) * SEQ + n) * QHEAD + 128 + j] = rv;
    } else {
        // q RoPE in-place: 32bh x 2048n x 64d space, 8 bf16 per thread
        int gid = (t - 1024) * 256 + threadIdx.x;
        int base = gid * 8;                    // flat index in q_pe space
        int bh  = base >> 17;                  // / (2048*64)
        int rem = base & 131071;
        int n   = rem >> 6;
        int dd  = rem & 63;                    // multiple of 8
        bf16* p = qf + ((size_t)bh * SEQ + n) * QHEAD + 128 + dd;
        bf16x8 v = *(const bf16x8*)p;
        bf16x8 o;
#pragma unroll
        for (int k = 0; k < 4; k++) {
            int i = (dd >> 1) + k;
            float trev = __builtin_amdgcn_exp2f(-(float)i * L2B32) * INV2PI;
            float sn, cs;
            rope_sincos((float)n, trev, sn, cs);
            float x1 = (float)v[2 * k], x2 = (float)v[2 * k + 1];
            o[2 * k]     = (bf16)(x1 * cs - x2 * sn);
            o[2 * k + 1] = (bf16)(x1 * sn + x2 * cs);
        }
        *(bf16x8*)p = o;
    }
}

// ---------------------------------------------------------------------------
// Flash attention, causal, FIXED-SHIFT softmax (no running max / no rescale).
// ROUND 7 body, FROZEN: T14 register-prefetch with fully SCALARIZED staging
// (rule #20). Three structural variants lost to it (L2-direct V: 172us;
// QBLK=128: 105us; this: 87us). Do not touch.
// ---------------------------------------------------------------------------
__global__ __launch_bounds__(256, 2) void attn_fa(
    const bf16* __restrict__ qf, const bf16* __restrict__ kf,
    const bf16* __restrict__ vT, bf16* __restrict__ attn_out)
{
    __shared__ bf16 Ks[64][200];
    __shared__ bf16 Vt[128][72];
    __shared__ bf16 Ps[4][16][72];

    const int bid = blockIdx.x;
    const int xcd = bid & 7, j = bid >> 3;     // j = 0..127
    const int qt = 31 - (j >> 2);              // heavy first
    const int bh = xcd + 8 * (j & 3);          // 4 bh per XCD
    const int b = bh >> 4, h = bh & 15;
    const int tid  = threadIdx.x;
    const int wave = tid >> 6, lane = tid & 63;
    const int quad = lane >> 4, l16 = lane & 15;

    bf16x8 aq[6];
    {
        const bf16* qbase = qf + ((size_t)bh * SEQ + qt * 64 + wave * 16 + l16) * QHEAD;
        for (int ks = 0; ks < 6; ks++)
            aq[ks] = *(const bf16x8*)(qbase + ks * 32 + quad * 8);
    }
    f32x4 o[8];
    for (int i = 0; i < 8; i++) o[i] = (f32x4){0.f, 0.f, 0.f, 0.f};
    float lp[4] = {0.f, 0.f, 0.f, 0.f};   // per-lane partial row sums

    // --- fully scalarized staging state (NO arrays: rule #20) ---------------
    const bf16 *kp0, *kp1, *kp2, *kp3, *kp4, *kp5;
    bf16 *kd0, *kd1, *kd2, *kd3, *kd4, *kd5;
    const bf16 *vp0, *vp1, *vp2, *vp3;
    bf16 *vd0, *vd1, *vd2, *vd3;
#define KINIT(I)                                                                \
    { int c = tid + I * 256; int r = c / 24, col = (c - r * 24) * 8;            \
      kp##I = kf + ((size_t)bh * SEQ + r) * QHEAD + col;                        \
      kd##I = &Ks[r][col]; }
#define VINIT(I)                                                                \
    { int c = tid + I * 256; int dv = c >> 3, g = c & 7;                        \
      vp##I = vT + ((size_t)bh * 128 + dv) * SEQ + g * 8;                       \
      vd##I = &Vt[dv][g * 8]; }
    KINIT(0) KINIT(1) KINIT(2) KINIT(3) KINIT(4) KINIT(5)
    VINIT(0) VINIT(1) VINIT(2) VINIT(3)
#undef KINIT
#undef VINIT

    uint4 kb0 = *(const uint4*)kp0, kb1 = *(const uint4*)kp1,
          kb2 = *(const uint4*)kp2, kb3 = *(const uint4*)kp3,
          kb4 = *(const uint4*)kp4, kb5 = *(const uint4*)kp5;
    uint4 vb0 = *(const uint4*)vp0, vb1 = *(const uint4*)vp1,
          vb2 = *(const uint4*)vp2, vb3 = *(const uint4*)vp3;

    for (int kt = 0; kt <= qt; kt++) {
        __syncthreads();                       // prev iter's LDS consumers done
        *(uint4*)kd0 = kb0; *(uint4*)kd1 = kb1; *(uint4*)kd2 = kb2;
        *(uint4*)kd3 = kb3; *(uint4*)kd4 = kb4; *(uint4*)kd5 = kb5;
        *(uint4*)vd0 = vb0; *(uint4*)vd1 = vb1;
        *(uint4*)vd2 = vb2; *(uint4*)vd3 = vb3;
        __syncthreads();                       // LDS visible

        if (kt < qt) {                         // prefetch kt+1; latency hides
            kp0 += 64 * QHEAD; kb0 = *(const uint4*)kp0;
            kp1 += 64 * QHEAD; kb1 = *(const uint4*)kp1;
            kp2 += 64 * QHEAD; kb2 = *(const uint4*)kp2;
            kp3 += 64 * QHEAD; kb3 = *(const uint4*)kp3;
            kp4 += 64 * QHEAD; kb4 = *(const uint4*)kp4;
            kp5 += 64 * QHEAD; kb5 = *(const uint4*)kp5;
            vp0 += 64; vb0 = *(const uint4*)vp0;
            vp1 += 64; vb1 = *(const uint4*)vp1;
            vp2 += 64; vb2 = *(const uint4*)vp2;
            vp3 += 64; vb3 = *(const uint4*)vp3;
        }

        f32x4 sacc[4];
        for (int nt = 0; nt < 4; nt++) sacc[nt] = (f32x4){0.f, 0.f, 0.f, 0.f};
        __builtin_amdgcn_s_setprio(1);
        for (int ks = 0; ks < 6; ks++)
            for (int nt = 0; nt < 4; nt++) {
                bf16x8 bk = *(const bf16x8*)&Ks[nt * 16 + l16][ks * 32 + quad * 8];
                sacc[nt] = __builtin_amdgcn_mfma_f32_16x16x32_bf16(aq[ks], bk, sacc[nt], 0, 0, 0);
            }
        __builtin_amdgcn_s_setprio(0);

        // p = 2^(sacc - CSHIFT); causal zeroing only on the diagonal tile
        const bool diag = (kt == qt);
#pragma unroll
        for (int r = 0; r < 4; r++) {
            const int qrow = wave * 16 + quad * 4 + r;
#pragma unroll
            for (int nt = 0; nt < 4; nt++) {
                float p;
                if (diag && (nt * 16 + l16 > qrow)) p = 0.f;
                else p = __builtin_amdgcn_exp2f(sacc[nt][r] - CSHIFT);
                lp[r] += p;
                Ps[wave][quad * 4 + r][nt * 16 + l16] = (bf16)p;
            }
        }
        __builtin_amdgcn_sched_barrier(0);   // Ps wave-private; pin order

        __builtin_amdgcn_s_setprio(1);
        for (int ks2 = 0; ks2 < 2; ks2++) {
            bf16x8 ap = *(const bf16x8*)&Ps[wave][l16][ks2 * 32 + quad * 8];
            for (int nv = 0; nv < 8; nv++) {
                bf16x8 bv = *(const bf16x8*)&Vt[nv * 16 + l16][ks2 * 32 + quad * 8];
                o[nv] = __builtin_amdgcn_mfma_f32_16x16x32_bf16(ap, bv, o[nv], 0, 0, 0);
            }
        }
        __builtin_amdgcn_s_setprio(0);
    }

    // single cross-lane reduction of the row sums (4 independent chains)
#pragma unroll
    for (int r = 0; r < 4; r++) {
        lp[r] += __shfl_xor(lp[r], 8);
        lp[r] += __shfl_xor(lp[r], 4);
        lp[r] += __shfl_xor(lp[r], 2);
        lp[r] += __shfl_xor(lp[r], 1);
    }

    for (int r = 0; r < 4; r++) {
        float inv = 1.f / lp[r];
        size_t row = (size_t)b * SEQ + qt * 64 + wave * 16 + quad * 4 + r;
        for (int nv = 0; nv < 8; nv++)
            attn_out[row * 2048 + h * 128 + nv * 16 + l16] = (bf16)(o[nv][r] * inv);
    }
}

// ---------------------------------------------------------------------------
extern "C" void kernel_launch(void* const* d_in, const int* in_sizes, int n_in,
                              void* d_out, int out_size, void* d_ws, size_t ws_size,
                              hipStream_t stream)
{
    const float* x    = (const float*)d_in[0];
    const float* Wqa  = (const float*)d_in[1];
    const float* Wqb  = (const float*)d_in[2];
    const float* Wkva = (const float*)d_in[3];
    const float* Wkvb = (const float*)d_in[4];
    const float* Wout = (const float*)d_in[5];
    float* out = (float*)d_out;

    char* ws = (char*)d_ws;
    size_t off = 0;
    auto alloc = [&](size_t elems) { char* p = ws + off; off += elems * sizeof(bf16); return (bf16*)p; };
    bf16* xb    = alloc((size_t)ROWS * 2048);   // reused as `attn` later
    bf16* WfT   = alloc((size_t)1152 * 2048);   // [WqaT(512) ; WkvaT(576) ; pad]
    bf16* WqbT  = alloc((size_t)3072 * 512);
    bf16* WkvbT = alloc((size_t)4096 * 512);
    bf16* WoutT = alloc((size_t)2048 * 2048);
    bf16* tc    = alloc((size_t)ROWS * 1152);   // [t1(512) | ckv(512) | k_pe(64) | pad]
    bf16* vT    = alloc((size_t)32 * 128 * SEQ);
    bf16* qf    = alloc((size_t)32 * SEQ * QHEAD);
    bf16* kf    = alloc((size_t)32 * SEQ * QHEAD);
    bf16* attn  = xb;                           // alias: xb dead after gemm13
    if (off > ws_size) return;                  // distinguishable failure

    dim3 blk(256);

    // convert + all weight transposes, one launch
    prep<<<dim3(18048), blk, 0, stream>>>(x, Wqa, Wqb, Wkva, Wkvb, Wout,
                                          xb, WfT, WqbT, WkvbT, WoutT);

    // GEMM1+3 fused: tc[:,0:1088] = x @ [Wqa|Wkva], K=2048 -- N64 tile,
    // grid 32x17 = 544 blocks (was 288 with 128x128: occupancy-starved)
    gemm_n64<bf16><<<dim3(32, 17), blk, 0, stream>>>(xb, 2048, WfT, 2048, tc, 1152, 1088, 2048);

    // GEMM2 (raw q -> qf) + GEMM4 (k_nope->kf, v direct-transposed -> vT)
    gemm_qkv<<<dim3(32, 56), blk, 0, stream>>>(tc, WqbT, WkvbT, qf, kf, vT);

    // k_pe RoPE broadcast + q RoPE (in-place on qf), one launch
    rope_vt<<<dim3(3072), blk, 0, stream>>>(tc, kf, qf);

    // flash attention: 1024 blocks, one qt each, heavy-first, XCD-stable bh
    attn_fa<<<dim3(1024), blk, 0, stream>>>(qf, kf, vT, attn);

    // GEMM5: out = attn @ Wout, K=2048 -- N64 tile, grid 32x32 = 1024 blocks
    // (was 512 with 128x128: 2 blocks/CU)
    gemm_n64<float><<<dim3(32, 32), blk, 0, stream>>>(attn, 2048, WoutT, 2048, out, 2048, 2048, 2048);
}